// Round 8
// baseline (514.736 us; speedup 1.0000x reference)
//
#include <hip/hip_runtime.h>
#include <stdint.h>

typedef __attribute__((ext_vector_type(8))) short bf16x8_t;   // 8 bf16 in 4 VGPRs
typedef __attribute__((ext_vector_type(16))) float f32x16_t;  // 32x32 MFMA acc

// ---------- helpers ----------

__device__ __forceinline__ unsigned short f2bf_rn(float f) {
    unsigned int u = __float_as_uint(f);
    u += 0x7fffu + ((u >> 16) & 1u);   // round-to-nearest-even
    return (unsigned short)(u >> 16);
}

// one packed byte (as int32 in [0,256)) -> two bf16 (q-8), low nibble = even k
__device__ __forceinline__ unsigned int dq2(int v) {
    float f0 = (float)((v & 15) - 8);
    float f1 = (float)(((v >> 4) & 15) - 8);
    return (__float_as_uint(f0) >> 16) | (__float_as_uint(f1) & 0xffff0000u);
}

__device__ __forceinline__ void gload_lds16(const void* g, void* l) {
    __builtin_amdgcn_global_load_lds(
        (__attribute__((address_space(1))) void*)g,
        (__attribute__((address_space(3))) void*)l, 16, 0, 0);
}

// ---------- pre-pass kernels: emit TILED kq-major bf16 layout ----------
// Dest layout (16B chunks): [rowblk256][kt(K/64)][kq(4)][slot(512)]
//   slot = (row&255)*2 + chp,  chp = (kc&1) ^ ((row>>2)&1)   (bank swizzle)
// Each kq block (8 KB) is CONTIGUOUS -> GEMM stages it linearly via
// global_load_lds; fragment ds_reads (16x16 OR 32x32 pattern) are
// conflict-free: any 8 consecutive rows with chp alternating by bit2 cover
// all 32 banks (verified R2/R4/R6: SQ_LDS_BANK_CONFLICT = 0).

__device__ __forceinline__ int tiled_dest(int r, int kc, int nkt) {
    int rb = r & 255;
    int kt = kc >> 3, kcl = kc & 7;
    int kq = kcl >> 1, ch = kcl & 1;
    int chp = ch ^ ((rb >> 2) & 1);
    return ((((r >> 8) * nkt + kt) * 4 + kq) << 9) + rb * 2 + chp;
}

__global__ void cvt_x_kernel(const float4* __restrict__ x4,
                             uint4* __restrict__ o4, int nchunks, int cpr, int nkt) {
    int stride = gridDim.x * blockDim.x;
    for (int i = blockIdx.x * blockDim.x + threadIdx.x; i < nchunks; i += stride) {
        int r = i / cpr, kc = i - r * cpr;
        float4 v0 = x4[2 * i];
        float4 v1 = x4[2 * i + 1];
        uint4 o;
        o.x = (unsigned)f2bf_rn(v0.x) | ((unsigned)f2bf_rn(v0.y) << 16);
        o.y = (unsigned)f2bf_rn(v0.z) | ((unsigned)f2bf_rn(v0.w) << 16);
        o.z = (unsigned)f2bf_rn(v1.x) | ((unsigned)f2bf_rn(v1.y) << 16);
        o.w = (unsigned)f2bf_rn(v1.z) | ((unsigned)f2bf_rn(v1.w) << 16);
        o4[tiled_dest(r, kc, nkt)] = o;
    }
}

__global__ void dequant_w_kernel(const int4* __restrict__ pw4,
                                 uint4* __restrict__ o4, int nchunks, int cpr, int nkt) {
    int stride = gridDim.x * blockDim.x;
    for (int i = blockIdx.x * blockDim.x + threadIdx.x; i < nchunks; i += stride) {
        int r = i / cpr, kc = i - r * cpr;
        int4 v = pw4[i];
        uint4 o;
        o.x = dq2(v.x); o.y = dq2(v.y); o.z = dq2(v.z); o.w = dq2(v.w);
        o4[tiled_dest(r, kc, nkt)] = o;
    }
}

// ---------- main GEMM: 256x256x64, 8 waves, R6 skeleton + 32x32x16 MFMA -----
// Per tile t (ONE sync point): vmcnt(0) [staging issued mid-body t-1, long in
// flight] -> s_barrier -> sched_barrier(0) -> two k-half steps, ORDER SKEWED
// by wave parity (h0 = wid&1 first): each step = 12 b128 frag reads + 16
// mfma_f32_32x32x16_bf16 (compiler-managed lgkm interleave, no pins).
// STAGE(t+1) (8 DMA) issued after the first read burst.
// MFMA: 256/tile/CU @ 8.07cyc = 2066 cyc floor (vs 2483 at 16x16 rate);
// skew keeps ~half the waves MFMAing while the other half reads LDS.
// Race ledger identical to R6 (RAW: own vmcnt(0)+barrier; WAR: STAGE(t+1)
// writes buf^1, last read in body t-1, data-complete before barrier(t)).
// 32x32x16 mappings: A/B lane: row|col = l&31, k = (l>>5)*8+i;
// C/D [m74/m101]: col = l&31, row = (reg&3)+8*(reg>>2)+4*(l>>5).

__global__ __launch_bounds__(512, 2) void qlin_gemm256(
    const short* __restrict__ Xb, const short* __restrict__ Wb,
    const float* __restrict__ scales, const float* __restrict__ bias,
    float* __restrict__ Y, int M, int N, int K)
{
    __shared__ short As[2][4][4096];   // [buf][kq][512 slots x 8 shorts] = 64 KB
    __shared__ short Bs[2][4][4096];   // 64 KB

    int nbm = M >> 8, nbn = N >> 8, nkt = K >> 6;
    int nwg = nbm * nbn;
    // bijective XCD swizzle (m204 form)
    int bid = blockIdx.x;
    int q8 = nwg >> 3, r8 = nwg & 7;
    int xcd = bid & 7, lid = bid >> 3;
    int wgid = (xcd < r8 ? xcd * (q8 + 1) : r8 * (q8 + 1) + (xcd - r8) * q8) + lid;
    int bm = wgid % nbm, bn = wgid / nbm;

    const short* ga = Xb + (size_t)bm * nkt * 16384;
    const short* gb = Wb + (size_t)bn * nkt * 16384;

    int tid = threadIdx.x, lane = tid & 63, wid = tid >> 6;
    int wr = wid >> 2, wc = wid & 3;          // 2x4 wave grid, per-wave out 128x64
    int lo5 = lane & 31, hi5 = lane >> 5;
    int chp = (hi5 ^ (lo5 >> 2)) & 1;         // lane-constant chunk swizzle
    int lsel = lo5 * 16 + chp * 8;            // within kq block (shorts)
    int aoff = wr * 2048;                     // (wr*128 rows)*16 shorts
    int boff = wc * 1024;                     // (wc*64 rows)*16 shorts

    f32x16_t acc[4][2] = {};                  // [mB][nB], each 32x32

#define STAGE(tt)                                                             \
    do {                                                                      \
        int b_ = (tt) & 1;                                                    \
        size_t base_ = (size_t)(tt) * 16384;                                  \
        _Pragma("unroll")                                                     \
        for (int kq_ = 0; kq_ < 4; ++kq_) {                                   \
            gload_lds16(ga + base_ + kq_ * 4096 + tid * 8,                    \
                        &As[b_][kq_][wid * 512]);                             \
            gload_lds16(gb + base_ + kq_ * 4096 + tid * 8,                    \
                        &Bs[b_][kq_][wid * 512]);                             \
        }                                                                     \
    } while (0)

#define READ_HALF(h_)                                                         \
    _Pragma("unroll")                                                         \
    for (int kk = 0; kk < 2; ++kk) {                                          \
        int kqo = ((h_) * 2 + kk) * 4096;                                     \
        _Pragma("unroll")                                                     \
        for (int nB = 0; nB < 2; ++nB)                                        \
            b[nB][kk] = *(const bf16x8_t*)&Bb[kqo + boff + nB * 512 + lsel];  \
        _Pragma("unroll")                                                     \
        for (int mB = 0; mB < 4; ++mB)                                        \
            a[mB][kk] = *(const bf16x8_t*)&Ab[kqo + aoff + mB * 512 + lsel];  \
    }

#define MFMA_HALF                                                             \
    __builtin_amdgcn_s_setprio(1);                                            \
    _Pragma("unroll")                                                         \
    for (int mB = 0; mB < 4; ++mB)                                            \
        _Pragma("unroll")                                                     \
        for (int nB = 0; nB < 2; ++nB)                                        \
            _Pragma("unroll")                                                 \
            for (int kk = 0; kk < 2; ++kk)                                    \
                acc[mB][nB] = __builtin_amdgcn_mfma_f32_32x32x16_bf16(        \
                    a[mB][kk], b[nB][kk], acc[mB][nB], 0, 0, 0);              \
    __builtin_amdgcn_s_setprio(0);

    // prologue: stage tile 0
    STAGE(0);

    const int hfirst = wid & 1;               // k-half skew by wave parity
    int nt = nkt;
    for (int t = 0; t < nt; ++t) {
        asm volatile("s_waitcnt vmcnt(0)" ::: "memory");
        __builtin_amdgcn_s_barrier();
        __builtin_amdgcn_sched_barrier(0);

        const short* Ab = &As[t & 1][0][0];
        const short* Bb = &Bs[t & 1][0][0];
        bf16x8_t a[4][2], b[2][2];

        // step 0: this wave's first k-half
        READ_HALF(hfirst)
        if (t + 1 < nt) STAGE(t + 1);
        MFMA_HALF

        // step 1: the other k-half
        READ_HALF(hfirst ^ 1)
        MFMA_HALF
    }
#undef STAGE
#undef READ_HALF
#undef MFMA_HALF

    int row_base = bm * 256 + wr * 128;
    int col_base = bn * 256 + wc * 64;
    #pragma unroll
    for (int nB = 0; nB < 2; ++nB) {
        int col = col_base + nB * 32 + lo5;
        float sc = scales[col], bi = bias[col];
        #pragma unroll
        for (int mB = 0; mB < 4; ++mB) {
            #pragma unroll
            for (int r = 0; r < 16; ++r) {
                int row = row_base + mB * 32 + (r & 3) + 8 * (r >> 2) + 4 * hi5;
                Y[(size_t)row * N + col] = acc[mB][nB][r] * sc + bi;
            }
        }
    }
}

// ---------- fallback (if ws too small / odd dims): tiled fp32, inline dequant --

__global__ __launch_bounds__(256) void qlin_fallback(
    const float* __restrict__ x, const int* __restrict__ pw,
    const float* __restrict__ scales, const float* __restrict__ bias,
    float* __restrict__ Y, int M, int N, int K)
{
    __shared__ float Xs[64][32];
    __shared__ float Ws[64][33];
    int bn = blockIdx.x, bm = blockIdx.y;
    int tid = threadIdx.x;
    int tr = tid >> 4, tc = tid & 15;
    float acc[4][4] = {};
    int K2 = K >> 1;
    for (int kt = 0; kt < K; kt += 32) {
        #pragma unroll
        for (int u = 0; u < 8; ++u) {
            int idx = u * 256 + tid;
            int rr = idx >> 5, cc = idx & 31;
            Xs[rr][cc] = x[(size_t)(bm * 64 + rr) * K + kt + cc];
        }
        #pragma unroll
        for (int u = 0; u < 4; ++u) {
            int idx = u * 256 + tid;
            int rr = idx >> 4, cc = idx & 15;
            int v = pw[(size_t)(bn * 64 + rr) * K2 + (kt >> 1) + cc];
            Ws[rr][cc * 2]     = (float)((v & 15) - 8);
            Ws[rr][cc * 2 + 1] = (float)(((v >> 4) & 15) - 8);
        }
        __syncthreads();
        #pragma unroll 8
        for (int kk = 0; kk < 32; ++kk) {
            float xv[4], wv[4];
            #pragma unroll
            for (int i = 0; i < 4; ++i) xv[i] = Xs[tr * 4 + i][kk];
            #pragma unroll
            for (int j = 0; j < 4; ++j) wv[j] = Ws[tc * 4 + j][kk];
            #pragma unroll
            for (int i = 0; i < 4; ++i)
                #pragma unroll
                for (int j = 0; j < 4; ++j)
                    acc[i][j] += xv[i] * wv[j];
        }
        __syncthreads();
    }
    #pragma unroll
    for (int j = 0; j < 4; ++j) {
        int n = bn * 64 + tc * 4 + j;
        float sc = scales[n], bi = bias[n];
        #pragma unroll
        for (int i = 0; i < 4; ++i) {
            int m = bm * 64 + tr * 4 + i;
            Y[(size_t)m * N + n] = acc[i][j] * sc + bi;
        }
    }
}

// ---------- host ----------

extern "C" void kernel_launch(void* const* d_in, const int* in_sizes, int n_in,
                              void* d_out, int out_size, void* d_ws, size_t ws_size,
                              hipStream_t stream) {
    const float* x      = (const float*)d_in[0];
    const int*   pw     = (const int*)d_in[1];
    const float* scales = (const float*)d_in[2];
    const float* bias   = (const float*)d_in[3];
    float*       y      = (float*)d_out;

    int N = in_sizes[2];                         // 11008
    long long pwe = in_sizes[1];                 // N*K/2
    int K = (int)((2 * pwe) / N);                // 4096
    int M = in_sizes[0] / K;                     // 4096

    size_t xb_bytes = (size_t)M * K * 2;
    size_t wb_bytes = (size_t)N * K * 2;

    bool fits = (ws_size >= xb_bytes + wb_bytes);
    bool dims_ok = (M % 256 == 0) && (N % 256 == 0) && (K % 64 == 0) && (K >= 128);

    if (fits && dims_ok) {
        short* xb = (short*)d_ws;
        short* wb = (short*)((char*)d_ws + xb_bytes);
        int cpr = K / 8;                         // 16B chunks per row
        int nkt = K / 64;
        int ncx = (int)((size_t)M * K / 8);
        hipLaunchKernelGGL(cvt_x_kernel, dim3(2048), dim3(256), 0, stream,
                           (const float4*)x, (uint4*)xb, ncx, cpr, nkt);
        int ncw = (int)(pwe / 4);                // = N*K/8
        hipLaunchKernelGGL(dequant_w_kernel, dim3(2048), dim3(256), 0, stream,
                           (const int4*)pw, (uint4*)wb, ncw, cpr, nkt);
        int nwg = (M / 256) * (N / 256);
        hipLaunchKernelGGL(qlin_gemm256, dim3(nwg), dim3(512), 0, stream,
                           xb, wb, scales, bias, y, M, N, K);
    } else {
        hipLaunchKernelGGL(qlin_fallback, dim3(N / 64, M / 64), dim3(256), 0, stream,
                           x, pw, scales, bias, y, M, N, K);
    }
}

// Round 9
// 473.521 us; speedup vs baseline: 1.0870x; 1.0870x over previous
//
#include <hip/hip_runtime.h>
#include <stdint.h>

typedef __attribute__((ext_vector_type(8))) short bf16x8_t;  // 8 bf16 in 4 VGPRs
typedef __attribute__((ext_vector_type(4))) float f32x4_t;   // MFMA accumulator

// ---------- helpers ----------

__device__ __forceinline__ unsigned short f2bf_rn(float f) {
    unsigned int u = __float_as_uint(f);
    u += 0x7fffu + ((u >> 16) & 1u);   // round-to-nearest-even
    return (unsigned short)(u >> 16);
}

// one packed byte -> two bf16 (q-8); low nibble = even k (matches reference)
__device__ __forceinline__ unsigned int dq2(int v) {
    float f0 = (float)((v & 15) - 8);
    float f1 = (float)(((v >> 4) & 15) - 8);
    return (__float_as_uint(f0) >> 16) | (__float_as_uint(f1) & 0xffff0000u);
}

__device__ __forceinline__ bf16x8_t unpack8(unsigned pv) {
    bf16x8_t r;
    #pragma unroll
    for (int j = 0; j < 4; ++j) {
        unsigned d = dq2((int)((pv >> (8 * j)) & 0xFF));
        r[2 * j]     = (short)(d & 0xFFFF);
        r[2 * j + 1] = (short)(d >> 16);
    }
    return r;
}

__device__ __forceinline__ void gload_lds16(const void* g, void* l) {
    __builtin_amdgcn_global_load_lds(
        (__attribute__((address_space(1))) void*)g,
        (__attribute__((address_space(3))) void*)l, 16, 0, 0);
}

// ---------- pre-pass 1: x fp32 -> bf16, TILED kq-major layout (unchanged) ---
// Dest (16B chunks): [rowblk256][kt(K/64)][kq(4)][slot(512)]
//   slot = (row&255)*2 + chp,  chp = (kc&1) ^ ((row>>2)&1)   (bank swizzle)
// GEMM stages each 8 KB kq block linearly via global_load_lds; A frag b128
// reads conflict-free (verified R2/R4/R6: SQ_LDS_BANK_CONFLICT = 0).

__device__ __forceinline__ int tiled_dest(int r, int kc, int nkt) {
    int rb = r & 255;
    int kt = kc >> 3, kcl = kc & 7;
    int kq = kcl >> 1, ch = kcl & 1;
    int chp = ch ^ ((rb >> 2) & 1);
    return ((((r >> 8) * nkt + kt) * 4 + kq) << 9) + rb * 2 + chp;
}

__global__ void cvt_x_kernel(const float4* __restrict__ x4,
                             uint4* __restrict__ o4, int nchunks, int cpr, int nkt) {
    int stride = gridDim.x * blockDim.x;
    for (int i = blockIdx.x * blockDim.x + threadIdx.x; i < nchunks; i += stride) {
        int r = i / cpr, kc = i - r * cpr;
        float4 v0 = x4[2 * i];
        float4 v1 = x4[2 * i + 1];
        uint4 o;
        o.x = (unsigned)f2bf_rn(v0.x) | ((unsigned)f2bf_rn(v0.y) << 16);
        o.y = (unsigned)f2bf_rn(v0.z) | ((unsigned)f2bf_rn(v0.w) << 16);
        o.z = (unsigned)f2bf_rn(v1.x) | ((unsigned)f2bf_rn(v1.y) << 16);
        o.w = (unsigned)f2bf_rn(v1.z) | ((unsigned)f2bf_rn(v1.w) << 16);
        o4[tiled_dest(r, kc, nkt)] = o;
    }
}

// ---------- pre-pass 2: W int32-per-byte -> BYTE-packed tiled (4x smaller) --
// In: pw int32[N][K/2], each elem holds one byte (two nibbles).
// Out (16B chunks): [nblk256][kt(K/64)][slot(512)], slot = rb*2 + half;
// chunk (rb,half) = bytes j = kt*32 + half*16 + [0..15] of row (k = 2j, 2j+1).
// Pure truncation int32->byte: bit-exact nibbles preserved.

__global__ void wpack_kernel(const int4* __restrict__ pw4,
                             uint4* __restrict__ o4, long long nchunks, int cpr) {
    long long i = (long long)blockIdx.x * blockDim.x + threadIdx.x;  // chunk id
    if (i >= nchunks) return;
    int r = (int)(i / cpr), c2 = (int)(i - (long long)r * cpr);
    const int4* src = pw4 + ((size_t)r * cpr + c2) * 4;   // 16 int32 = 64B
    int4 v0 = src[0], v1 = src[1], v2 = src[2], v3 = src[3];
    uint4 o;
    o.x = (v0.x & 255) | ((v0.y & 255) << 8) | ((v0.z & 255) << 16) | ((unsigned)(v0.w & 255) << 24);
    o.y = (v1.x & 255) | ((v1.y & 255) << 8) | ((v1.z & 255) << 16) | ((unsigned)(v1.w & 255) << 24);
    o.z = (v2.x & 255) | ((v2.y & 255) << 8) | ((v2.z & 255) << 16) | ((unsigned)(v2.w & 255) << 24);
    o.w = (v3.x & 255) | ((v3.y & 255) << 8) | ((v3.z & 255) << 16) | ((unsigned)(v3.w & 255) << 24);
    int nkt = cpr >> 1;
    size_t dst = (((size_t)(r >> 8) * nkt + (c2 >> 1)) << 9) + (r & 255) * 2 + (c2 & 1);
    o4[dst] = o;
}

// ---------- main GEMM: 256x256x64, 8 waves, R6 loose schedule + packed B ----
// Per tile t (ONE sync point): vmcnt(0) [5 DMA issued mid-body t-1, long in
// flight] -> s_barrier -> sched_barrier(0) -> issue 8 B b32 reads + 16 A b128
// reads -> STAGE(t+1) (4 A-DMA + 1 B-DMA) -> unpack B (VALU, overlaps A-read
// streaming) -> 64 MFMA, compiler-managed lgkm interleave (no pins, no
// setprio: not phase-split, m190). B staged PACKED (8 KB/tile vs 32): LDS
// traffic/tile 260 KB -> 184 KB (measured LDS path was the 2800-cyc critical
// path vs MFMA 2066). b32 frag reads are 4-way bank-conflicted (~1.58x on 8
// cheap reads - accepted, m136). Race ledger identical to R6.

__global__ __launch_bounds__(512, 2) void qlin_gemm256(
    const short* __restrict__ Xb, const unsigned* __restrict__ Wp,
    const float* __restrict__ scales, const float* __restrict__ bias,
    float* __restrict__ Y, int M, int N, int K)
{
    __shared__ short As[2][4][4096];       // 64 KB: A bf16 kq-major
    __shared__ unsigned Bp[2][2048];       // 16 KB: B packed bytes [row][8 uints]

    int nbm = M >> 8, nbn = N >> 8, nkt = K >> 6;
    int nwg = nbm * nbn;
    // bijective XCD swizzle (m204 form)
    int bid = blockIdx.x;
    int q8 = nwg >> 3, r8 = nwg & 7;
    int xcd = bid & 7, lid = bid >> 3;
    int wgid = (xcd < r8 ? xcd * (q8 + 1) : r8 * (q8 + 1) + (xcd - r8) * q8) + lid;
    int bm = wgid % nbm, bn = wgid / nbm;

    const short* ga = Xb + (size_t)bm * nkt * 16384;
    const char*  gw = (const char*)Wp + (size_t)bn * nkt * 8192;

    int tid = threadIdx.x, lane = tid & 63, wid = tid >> 6;
    int wr = wid >> 2, wc = wid & 3;          // 2x4 wave grid, per-wave out 128x64
    int fr = lane & 15, fq = lane >> 4;       // frag row / k-subchunk
    int chp = (fq & 1) ^ ((fr >> 2) & 1);     // lane-constant chunk swizzle (A)

    f32x4_t acc[8][4] = {};

    int lsel = (fq >> 1) * 4096 + fr * 16 + chp * 8;
    int aoff = wr * 2048;                     // (wr*128 rows)*16 shorts
    int bq0  = (wc * 64 + fr) * 8 + fq;       // B uint idx base: row*8 + h*4 + fq

#define STAGE(tt)                                                             \
    do {                                                                      \
        int b_ = (tt) & 1;                                                    \
        size_t abase_ = (size_t)(tt) * 16384;                                 \
        _Pragma("unroll")                                                     \
        for (int kq_ = 0; kq_ < 4; ++kq_) {                                   \
            gload_lds16(ga + abase_ + kq_ * 4096 + tid * 8,                   \
                        &As[b_][kq_][wid * 512]);                             \
        }                                                                     \
        gload_lds16(gw + (size_t)(tt) * 8192 + tid * 16,                      \
                    &Bp[b_][wid * 256]);                                      \
    } while (0)

    // prologue: stage tile 0
    STAGE(0);

    int nt = nkt;
    for (int t = 0; t < nt; ++t) {
        asm volatile("s_waitcnt vmcnt(0)" ::: "memory");
        __builtin_amdgcn_s_barrier();
        __builtin_amdgcn_sched_barrier(0);

        const short*    Ab = &As[t & 1][0][0];
        const unsigned* Bq = &Bp[t & 1][0];

        // B packed reads first (8 x b32; retire first in the in-order queue)
        unsigned pv[4][2];
        #pragma unroll
        for (int n = 0; n < 4; ++n)
            #pragma unroll
            for (int h = 0; h < 2; ++h)
                pv[n][h] = Bq[bq0 + n * 128 + h * 4];

        // A frag reads (16 x b128), stream under the MFMA chase
        bf16x8_t a[8][2];
        #pragma unroll
        for (int m = 0; m < 8; ++m)
            #pragma unroll
            for (int h = 0; h < 2; ++h)
                a[m][h] = *(const bf16x8_t*)&Ab[h * 8192 + lsel + aoff + m * 256];

        if (t + 1 < nt) STAGE(t + 1);

        // unpack B (VALU; compiler waits only on the 8 early b32s)
        bf16x8_t b[4][2];
        #pragma unroll
        for (int n = 0; n < 4; ++n)
            #pragma unroll
            for (int h = 0; h < 2; ++h)
                b[n][h] = unpack8(pv[n][h]);

        #pragma unroll
        for (int m = 0; m < 8; ++m)
            #pragma unroll
            for (int h = 0; h < 2; ++h)
                #pragma unroll
                for (int n = 0; n < 4; ++n)
                    acc[m][n] = __builtin_amdgcn_mfma_f32_16x16x32_bf16(
                        a[m][h], b[n][h], acc[m][n], 0, 0, 0);
    }
#undef STAGE

    int row_base = bm * 256 + wr * 128;
    int col_base = bn * 256 + wc * 64;
    #pragma unroll
    for (int n = 0; n < 4; ++n) {
        int col = col_base + n * 16 + fr;
        float sc = scales[col], bi = bias[col];
        #pragma unroll
        for (int m = 0; m < 8; ++m) {
            int m0 = row_base + m * 16 + fq * 4;
            #pragma unroll
            for (int r2 = 0; r2 < 4; ++r2)
                Y[(size_t)(m0 + r2) * N + col] = acc[m][n][r2] * sc + bi;
        }
    }
}

// ---------- fallback (if ws too small / odd dims): tiled fp32, inline dequant --

__global__ __launch_bounds__(256) void qlin_fallback(
    const float* __restrict__ x, const int* __restrict__ pw,
    const float* __restrict__ scales, const float* __restrict__ bias,
    float* __restrict__ Y, int M, int N, int K)
{
    __shared__ float Xs[64][32];
    __shared__ float Ws[64][33];
    int bn = blockIdx.x, bm = blockIdx.y;
    int tid = threadIdx.x;
    int tr = tid >> 4, tc = tid & 15;
    float acc[4][4] = {};
    int K2 = K >> 1;
    for (int kt = 0; kt < K; kt += 32) {
        #pragma unroll
        for (int u = 0; u < 8; ++u) {
            int idx = u * 256 + tid;
            int rr = idx >> 5, cc = idx & 31;
            Xs[rr][cc] = x[(size_t)(bm * 64 + rr) * K + kt + cc];
        }
        #pragma unroll
        for (int u = 0; u < 4; ++u) {
            int idx = u * 256 + tid;
            int rr = idx >> 4, cc = idx & 15;
            int v = pw[(size_t)(bn * 64 + rr) * K2 + (kt >> 1) + cc];
            Ws[rr][cc * 2]     = (float)((v & 15) - 8);
            Ws[rr][cc * 2 + 1] = (float)(((v >> 4) & 15) - 8);
        }
        __syncthreads();
        #pragma unroll 8
        for (int kk = 0; kk < 32; ++kk) {
            float xv[4], wv[4];
            #pragma unroll
            for (int i = 0; i < 4; ++i) xv[i] = Xs[tr * 4 + i][kk];
            #pragma unroll
            for (int j = 0; j < 4; ++j) wv[j] = Ws[tc * 4 + j][kk];
            #pragma unroll
            for (int i = 0; i < 4; ++i)
                #pragma unroll
                for (int j = 0; j < 4; ++j)
                    acc[i][j] += xv[i] * wv[j];
        }
        __syncthreads();
    }
    #pragma unroll
    for (int j = 0; j < 4; ++j) {
        int n = bn * 64 + tc * 4 + j;
        float sc = scales[n], bi = bias[n];
        #pragma unroll
        for (int i = 0; i < 4; ++i) {
            int m = bm * 64 + tr * 4 + i;
            Y[(size_t)m * N + n] = acc[i][j] * sc + bi;
        }
    }
}

// ---------- host ----------

extern "C" void kernel_launch(void* const* d_in, const int* in_sizes, int n_in,
                              void* d_out, int out_size, void* d_ws, size_t ws_size,
                              hipStream_t stream) {
    const float* x      = (const float*)d_in[0];
    const int*   pw     = (const int*)d_in[1];
    const float* scales = (const float*)d_in[2];
    const float* bias   = (const float*)d_in[3];
    float*       y      = (float*)d_out;

    int N = in_sizes[2];                         // 11008
    long long pwe = in_sizes[1];                 // N*K/2 (int32 elems, 1 byte each)
    int K = (int)((2 * pwe) / N);                // 4096
    int M = in_sizes[0] / K;                     // 4096

    size_t xb_bytes = (size_t)M * K * 2;         // bf16 A
    size_t wp_bytes = (size_t)N * (K / 2);       // byte-packed W

    bool fits = (ws_size >= xb_bytes + wp_bytes);
    bool dims_ok = (M % 256 == 0) && (N % 256 == 0) && (K % 64 == 0) && (K >= 128);

    if (fits && dims_ok) {
        short*    xb = (short*)d_ws;
        unsigned* wp = (unsigned*)((char*)d_ws + xb_bytes);
        int cpr = K / 8;                         // 16B chunks per A row
        int nkt = K / 64;
        int ncx = (int)((size_t)M * K / 8);
        hipLaunchKernelGGL(cvt_x_kernel, dim3(2048), dim3(256), 0, stream,
                           (const float4*)x, (uint4*)xb, ncx, cpr, nkt);
        long long wchunks = (long long)N * (K / 32);   // 16B out-chunks
        int wcpr = K / 32;                             // chunks per W row
        int wblocks = (int)((wchunks + 511) / 512);
        hipLaunchKernelGGL(wpack_kernel, dim3(wblocks), dim3(512), 0, stream,
                           (const int4*)pw, (uint4*)wp, wchunks, wcpr);
        int nwg = (M / 256) * (N / 256);
        hipLaunchKernelGGL(qlin_gemm256, dim3(nwg), dim3(512), 0, stream,
                           xb, wp, scales, bias, y, M, N, K);
    } else {
        hipLaunchKernelGGL(qlin_fallback, dim3(N / 64, M / 64), dim3(256), 0, stream,
                           x, pw, scales, bias, y, M, N, K);
    }
}

// Round 10
// 238.615 us; speedup vs baseline: 2.1572x; 1.9845x over previous
//
#include <hip/hip_runtime.h>
#include <stdint.h>

typedef __attribute__((ext_vector_type(4))) int   i32x4_t;   // i8-MFMA operands/acc
typedef __attribute__((ext_vector_type(4))) float f32x4_t;

__device__ __forceinline__ void gload_lds16(const void* g, void* l) {
    __builtin_amdgcn_global_load_lds(
        (__attribute__((address_space(1))) void*)g,
        (__attribute__((address_space(3))) void*)l, 16, 0, 0);
}

// ---------- tiled int8 layout (both A and B) ----------
// 16B chunks: [rowblk256][kt(K/64)][row(256)][c(4)], stored chunk index
// c_sw = c ^ ((row>>1)&3). Each (rowblk,kt) block = 16 KB contiguous ->
// staged linearly via global_load_lds. Frag b128 reads (row = base16 + fr,
// chunk = (lane>>4) ^ ((fr>>1)&3)): every 8-lane group covers all 32 banks
// exactly once (parity-of-row x chunk argument) -> conflict-free.

// ---------- pre-pass 1: x fp32 -> int8 per-row dynamic quant ----------
// One block per row: pass1 max|x|, pass2 quantize q = rint(x*127/rmax).
// rowscale[row] = rmax/127. Exact-safe: no clamping needed.

__global__ __launch_bounds__(256) void quant_x_kernel(
    const float* __restrict__ x, uint4* __restrict__ o4,
    float* __restrict__ rowscale, int K, int nkt)
{
    __shared__ float red[256];
    int row = blockIdx.x, tid = threadIdx.x;
    const float4* xr = (const float4*)(x + (size_t)row * K);
    int nch = K >> 4;                       // 16B out-chunks per row

    float lmax = 0.f;
    for (int c = tid; c < nch; c += 256) {
        #pragma unroll
        for (int j = 0; j < 4; ++j) {
            float4 v = xr[c * 4 + j];
            lmax = fmaxf(lmax, fmaxf(fmaxf(fabsf(v.x), fabsf(v.y)),
                                     fmaxf(fabsf(v.z), fabsf(v.w))));
        }
    }
    red[tid] = lmax;
    __syncthreads();
    #pragma unroll
    for (int s = 128; s > 0; s >>= 1) {
        if (tid < s) red[tid] = fmaxf(red[tid], red[tid + s]);
        __syncthreads();
    }
    float rmax = red[0];
    float inv = (rmax > 0.f) ? 127.f / rmax : 0.f;
    if (tid == 0) rowscale[row] = rmax * (1.f / 127.f);

    int rb = row & 255;
    int sw = (rb >> 1) & 3;
    size_t blkbase = ((size_t)(row >> 8) * nkt) << 10;   // in 16B chunks
    for (int c = tid; c < nch; c += 256) {
        unsigned u[4];
        #pragma unroll
        for (int j = 0; j < 4; ++j) {
            float4 v = xr[c * 4 + j];
            int q0 = (int)rintf(v.x * inv), q1 = (int)rintf(v.y * inv);
            int q2 = (int)rintf(v.z * inv), q3 = (int)rintf(v.w * inv);
            u[j] = (q0 & 255) | ((q1 & 255) << 8) | ((q2 & 255) << 16)
                 | ((unsigned)(q3 & 255) << 24);
        }
        int kt = c >> 2, cc = c & 3;
        size_t dst = blkbase + ((size_t)kt << 10) + rb * 4 + (cc ^ sw);
        o4[dst] = make_uint4(u[0], u[1], u[2], u[3]);
    }
}

// ---------- pre-pass 2: packed int4 (1 byte per int32) -> int8 tiled ----
// Thread handles one 16B out-chunk = 16 k-values = 8 input int32.
// low nibble = even k (reference order); q - 8 exact in int8.

__global__ __launch_bounds__(256) void quant_w_kernel(
    const int4* __restrict__ pw4, uint4* __restrict__ o4,
    long long nchunks, int cpr /* = K/16 */, int nkt)
{
    long long i = (long long)blockIdx.x * blockDim.x + threadIdx.x;
    if (i >= nchunks) return;
    int r = (int)(i / cpr), c16 = (int)(i - (long long)r * cpr);
    const int4* src = pw4 + ((size_t)r * cpr + c16) * 2;   // 8 int32 = 32B
    int4 v0 = src[0], v1 = src[1];
    int bytes[8] = { v0.x & 255, v0.y & 255, v0.z & 255, v0.w & 255,
                     v1.x & 255, v1.y & 255, v1.z & 255, v1.w & 255 };
    unsigned u[4];
    #pragma unroll
    for (int j = 0; j < 4; ++j) {
        int b0 = bytes[2 * j], b1 = bytes[2 * j + 1];
        int q0 = (b0 & 15) - 8, q1 = ((b0 >> 4) & 15) - 8;
        int q2 = (b1 & 15) - 8, q3 = ((b1 >> 4) & 15) - 8;
        u[j] = (q0 & 255) | ((q1 & 255) << 8) | ((q2 & 255) << 16)
             | ((unsigned)(q3 & 255) << 24);
    }
    int rb = r & 255, kt = c16 >> 2, cc = c16 & 3;
    size_t dst = (((size_t)(r >> 8) * nkt + kt) << 10) + rb * 4
               + (cc ^ ((rb >> 1) & 3));
    o4[dst] = make_uint4(u[0], u[1], u[2], u[3]);
}

// ---------- main GEMM: 256x256x64 int8, R6 loose schedule (unchanged) ----
// Per tile t (ONE sync point): vmcnt(0) -> s_barrier -> sched_barrier(0) ->
// 12 frag b128 reads -> STAGE(t+1) (4 DMA) -> 32 mfma_i32_16x16x64_i8,
// compiler-managed lgkm interleave. LDS traffic/tile: 96KB reads + 32KB
// DMA writes (was 192+64 bf16); MFMA floor ~1300 cyc (was 2483).
// Race ledger identical to R6. Epilogue: y = acc_i32 * srow*scol + bias.

__global__ __launch_bounds__(512, 2) void qlin_gemm256(
    const char* __restrict__ Xq, const char* __restrict__ Wq,
    const float* __restrict__ rowscale,
    const float* __restrict__ scales, const float* __restrict__ bias,
    float* __restrict__ Y, int M, int N, int K)
{
    __shared__ char As[2][16384];
    __shared__ char Bs[2][16384];

    int nbm = M >> 8, nbn = N >> 8, nkt = K >> 6;
    int nwg = nbm * nbn;
    // bijective XCD swizzle (m204 form)
    int bid = blockIdx.x;
    int q8 = nwg >> 3, r8 = nwg & 7;
    int xcd = bid & 7, lid = bid >> 3;
    int wgid = (xcd < r8 ? xcd * (q8 + 1) : r8 * (q8 + 1) + (xcd - r8) * q8) + lid;
    int bm = wgid % nbm, bn = wgid / nbm;

    const char* ga = Xq + (size_t)bm * nkt * 16384;
    const char* gb = Wq + (size_t)bn * nkt * 16384;

    int tid = threadIdx.x, lane = tid & 63, wid = tid >> 6;
    int wr = wid >> 2, wc = wid & 3;          // 2x4 wave grid, per-wave out 128x64
    int fr = lane & 15, fq = lane >> 4;       // frag row / k-chunk (16 int8)
    int csw = fq ^ ((fr >> 1) & 3);           // lane-constant chunk swizzle
    int lsel = fr * 64 + csw * 16;            // byte offset within 16KB tile
    int aoff = wr * 8192;                     // wr*128 rows * 64B
    int boff = wc * 4096;                     // wc*64 rows * 64B

    i32x4_t acc[8][4] = {};

#define STAGE(tt)                                                             \
    do {                                                                      \
        int b_ = (tt) & 1;                                                    \
        size_t base_ = (size_t)(tt) * 16384;                                  \
        _Pragma("unroll")                                                     \
        for (int h_ = 0; h_ < 2; ++h_) {                                      \
            gload_lds16(ga + base_ + h_ * 8192 + tid * 16,                    \
                        &As[b_][h_ * 8192 + wid * 1024]);                     \
            gload_lds16(gb + base_ + h_ * 8192 + tid * 16,                    \
                        &Bs[b_][h_ * 8192 + wid * 1024]);                     \
        }                                                                     \
    } while (0)

    // prologue: stage tile 0
    STAGE(0);

    int nt = nkt;
    for (int t = 0; t < nt; ++t) {
        asm volatile("s_waitcnt vmcnt(0)" ::: "memory");
        __builtin_amdgcn_s_barrier();
        __builtin_amdgcn_sched_barrier(0);

        const char* Ab = &As[t & 1][0];
        const char* Bb = &Bs[t & 1][0];

        i32x4_t a[8], b[4];
        #pragma unroll
        for (int n = 0; n < 4; ++n)
            b[n] = *(const i32x4_t*)&Bb[boff + n * 1024 + lsel];
        #pragma unroll
        for (int m = 0; m < 8; ++m)
            a[m] = *(const i32x4_t*)&Ab[aoff + m * 1024 + lsel];

        if (t + 1 < nt) STAGE(t + 1);

        __builtin_amdgcn_s_setprio(1);
        #pragma unroll
        for (int m = 0; m < 8; ++m)
            #pragma unroll
            for (int n = 0; n < 4; ++n)
                acc[m][n] = __builtin_amdgcn_mfma_i32_16x16x64_i8(
                    a[m], b[n], acc[m][n], 0, 0, 0);
        __builtin_amdgcn_s_setprio(0);
    }
#undef STAGE

    int row_base = bm * 256 + wr * 128;
    int col_base = bn * 256 + wc * 64;
    float rs[8][4];
    #pragma unroll
    for (int m = 0; m < 8; ++m)
        #pragma unroll
        for (int r2 = 0; r2 < 4; ++r2)
            rs[m][r2] = rowscale[row_base + m * 16 + fq * 4 + r2];
    #pragma unroll
    for (int n = 0; n < 4; ++n) {
        int col = col_base + n * 16 + fr;
        float sc = scales[col], bi = bias[col];
        #pragma unroll
        for (int m = 0; m < 8; ++m) {
            int m0 = row_base + m * 16 + fq * 4;
            #pragma unroll
            for (int r2 = 0; r2 < 4; ++r2)
                Y[(size_t)(m0 + r2) * N + col] =
                    (float)acc[m][n][r2] * (rs[m][r2] * sc) + bi;
        }
    }
}

// ---------- fallback (if ws too small / odd dims): tiled fp32, inline dequant --

__global__ __launch_bounds__(256) void qlin_fallback(
    const float* __restrict__ x, const int* __restrict__ pw,
    const float* __restrict__ scales, const float* __restrict__ bias,
    float* __restrict__ Y, int M, int N, int K)
{
    __shared__ float Xs[64][32];
    __shared__ float Ws[64][33];
    int bn = blockIdx.x, bm = blockIdx.y;
    int tid = threadIdx.x;
    int tr = tid >> 4, tc = tid & 15;
    float acc[4][4] = {};
    int K2 = K >> 1;
    for (int kt = 0; kt < K; kt += 32) {
        #pragma unroll
        for (int u = 0; u < 8; ++u) {
            int idx = u * 256 + tid;
            int rr = idx >> 5, cc = idx & 31;
            Xs[rr][cc] = x[(size_t)(bm * 64 + rr) * K + kt + cc];
        }
        #pragma unroll
        for (int u = 0; u < 4; ++u) {
            int idx = u * 256 + tid;
            int rr = idx >> 4, cc = idx & 15;
            int v = pw[(size_t)(bn * 64 + rr) * K2 + (kt >> 1) + cc];
            Ws[rr][cc * 2]     = (float)((v & 15) - 8);
            Ws[rr][cc * 2 + 1] = (float)(((v >> 4) & 15) - 8);
        }
        __syncthreads();
        #pragma unroll 8
        for (int kk = 0; kk < 32; ++kk) {
            float xv[4], wv[4];
            #pragma unroll
            for (int i = 0; i < 4; ++i) xv[i] = Xs[tr * 4 + i][kk];
            #pragma unroll
            for (int j = 0; j < 4; ++j) wv[j] = Ws[tc * 4 + j][kk];
            #pragma unroll
            for (int i = 0; i < 4; ++i)
                #pragma unroll
                for (int j = 0; j < 4; ++j)
                    acc[i][j] += xv[i] * wv[j];
        }
        __syncthreads();
    }
    #pragma unroll
    for (int j = 0; j < 4; ++j) {
        int n = bn * 64 + tc * 4 + j;
        float sc = scales[n], bi = bias[n];
        #pragma unroll
        for (int i = 0; i < 4; ++i) {
            int m = bm * 64 + tr * 4 + i;
            Y[(size_t)m * N + n] = acc[i][j] * sc + bi;
        }
    }
}

// ---------- host ----------

extern "C" void kernel_launch(void* const* d_in, const int* in_sizes, int n_in,
                              void* d_out, int out_size, void* d_ws, size_t ws_size,
                              hipStream_t stream) {
    const float* x      = (const float*)d_in[0];
    const int*   pw     = (const int*)d_in[1];
    const float* scales = (const float*)d_in[2];
    const float* bias   = (const float*)d_in[3];
    float*       y      = (float*)d_out;

    int N = in_sizes[2];                         // 11008
    long long pwe = in_sizes[1];                 // N*K/2 (int32 elems, 1 byte each)
    int K = (int)((2 * pwe) / N);                // 4096
    int M = in_sizes[0] / K;                     // 4096

    size_t xq_bytes = (size_t)M * K;             // int8 A
    size_t wq_bytes = (size_t)N * K;             // int8 W
    size_t rs_bytes = (size_t)M * 4;             // rowscale

    bool fits = (ws_size >= xq_bytes + wq_bytes + rs_bytes);
    bool dims_ok = (M % 256 == 0) && (N % 256 == 0) && (K % 64 == 0) && (K >= 128);

    if (fits && dims_ok) {
        char*  xq = (char*)d_ws;
        char*  wq = (char*)d_ws + xq_bytes;
        float* rs = (float*)((char*)d_ws + xq_bytes + wq_bytes);
        int nkt = K / 64;
        hipLaunchKernelGGL(quant_x_kernel, dim3(M), dim3(256), 0, stream,
                           x, (uint4*)xq, rs, K, nkt);
        long long wchunks = (long long)N * (K / 16);
        int wblocks = (int)((wchunks + 255) / 256);
        hipLaunchKernelGGL(quant_w_kernel, dim3(wblocks), dim3(256), 0, stream,
                           (const int4*)pw, (uint4*)wq, wchunks, K / 16, nkt);
        int nwg = (M / 256) * (N / 256);
        hipLaunchKernelGGL(qlin_gemm256, dim3(nwg), dim3(512), 0, stream,
                           xq, wq, rs, scales, bias, y, M, N, K);
    } else {
        hipLaunchKernelGGL(qlin_fallback, dim3(N / 64, M / 64), dim3(256), 0, stream,
                           x, pw, scales, bias, y, M, N, K);
    }
}